// Round 8
// baseline (72.149 us; speedup 1.0000x reference)
//
#include <hip/hip_runtime.h>
#include <hip/hip_bf16.h>

typedef short bf16x8 __attribute__((ext_vector_type(8)));
typedef float f32x4  __attribute__((ext_vector_type(4)));

constexpr int HW = 4096;   // 64*64 pixels
constexpr int CT = 31;     // time channels
constexpr int CP = 128;    // poi channels
constexpr int CO = 64;     // output channels
constexpr int NB = 32;     // batch
constexpr int NTILES = NB * (HW / 16);   // 8192 tiles of 16 px

__device__ __forceinline__ short f2bf(float x) {
    __hip_bfloat16 h = __float2bfloat16(x);
    return *reinterpret_cast<short*>(&h);
}

// One wave computes a 64(o) x 16(px) output tile via mfma_f32_16x16x32_bf16.
// Weights live ONCE in per-lane VGPR fragments (no streaming, no LDS, no barriers).
// Stage-1 time-MLP fused: 2 MFMAs + in-register relu/dot + 2 shfl_xor.
__global__ void poi_mfma_kernel(const float* __restrict__ poi,
                                const float* __restrict__ tin,
                                const float* __restrict__ wm,
                                const float* __restrict__ bm,
                                const float* __restrict__ wf,
                                const float* __restrict__ bf,
                                const float* __restrict__ wc,
                                const float* __restrict__ bc,
                                float* __restrict__ out)
{
    const int lane = threadIdx.x & 63;
    const int m = lane & 15;          // fragment row (A) / col (B,D): o-row or px
    const int g = lane >> 4;          // 4-lane group: k-subrange / D row-group
    const int gw = blockIdx.x * 4 + (threadIdx.x >> 6);   // global wave id
    const int nw = gridDim.x * 4;

    // ---------- one-time weight fragments (wc is 32 KB, L2-resident) ----------
    bf16x8 wcf[4][4];                 // [o-subtile s][k-frag kf]
    #pragma unroll
    for (int s = 0; s < 4; ++s)
      #pragma unroll
      for (int kf = 0; kf < 4; ++kf)
        #pragma unroll
        for (int j = 0; j < 8; ++j)
          wcf[s][kf][j] = f2bf(wc[(s * 16 + m) * CP + kf * 32 + g * 8 + j]);

    bf16x8 wmf[2];                    // wm: 32x31 padded to 32x32
    #pragma unroll
    for (int t = 0; t < 2; ++t)
      #pragma unroll
      for (int j = 0; j < 8; ++j) {
        const int c = g * 8 + j;
        wmf[t][j] = (c < CT) ? f2bf(wm[(t * 16 + m) * CT + c]) : (short)0;
      }

    float wff[8]; f32x4 bmf[2], bcf[4];
    #pragma unroll
    for (int t = 0; t < 2; ++t)
      #pragma unroll
      for (int r = 0; r < 4; ++r) {
        wff[t * 4 + r] = wf[t * 16 + g * 4 + r];   // z D-row -> hidden index
        bmf[t][r]      = bm[t * 16 + g * 4 + r];   // bias as MFMA C-operand
      }
    #pragma unroll
    for (int s = 0; s < 4; ++s)
      #pragma unroll
      for (int r = 0; r < 4; ++r)
        bcf[s][r] = bc[s * 16 + g * 4 + r];
    const float bfv = bf[0];

    // ---------- grid-stride over 16-px tiles ----------
    for (int tile = gw; tile < NTILES; tile += nw) {
        const int b  = tile >> 8;                    // 256 tiles per image
        const int px = ((tile & 255) << 4) + m;

        // ---- stage 1: tval = relu(wf . relu(wm@time + bm) + bf) ----
        const float* tb = tin + (size_t)b * CT * HW + px;
        bf16x8 tf;
        #pragma unroll
        for (int j = 0; j < 8; ++j) {
            const int c = g * 8 + j;
            tf[j] = (c < CT) ? f2bf(tb[(size_t)c * HW]) : (short)0;
        }
        f32x4 z0 = __builtin_amdgcn_mfma_f32_16x16x32_bf16(wmf[0], tf, bmf[0], 0, 0, 0);
        f32x4 z1 = __builtin_amdgcn_mfma_f32_16x16x32_bf16(wmf[1], tf, bmf[1], 0, 0, 0);
        float s1 = 0.f;
        #pragma unroll
        for (int r = 0; r < 4; ++r) {
            s1 = fmaf(fmaxf(z0[r], 0.f), wff[r],     s1);
            s1 = fmaf(fmaxf(z1[r], 0.f), wff[4 + r], s1);
        }
        s1 += __shfl_xor(s1, 16, 64);                // combine lane-groups (same px)
        s1 += __shfl_xor(s1, 32, 64);
        const float tval = fmaxf(s1 + bfv, 0.f);

        // ---- stage 2: acc[s] = wc_subtile_s @ poi_tile (K=128 in 4 MFMAs) ----
        const float* pb = poi + (size_t)b * CP * HW + px;
        bf16x8 pf[4];
        #pragma unroll
        for (int kf = 0; kf < 4; ++kf)
          #pragma unroll
          for (int j = 0; j < 8; ++j)
            pf[kf][j] = f2bf(pb[(size_t)(kf * 32 + g * 8 + j) * HW]);

        f32x4 acc[4];
        #pragma unroll
        for (int s = 0; s < 4; ++s) {
            f32x4 a = {0.f, 0.f, 0.f, 0.f};
            #pragma unroll
            for (int kf = 0; kf < 4; ++kf)
                a = __builtin_amdgcn_mfma_f32_16x16x32_bf16(wcf[s][kf], pf[kf], a, 0, 0, 0);
            acc[s] = a;
        }

        // ---- epilogue: out[o][px] = tval * acc + bc[o];  o = s*16 + 4g + r ----
        float* ob = out + (size_t)b * CO * HW + px;
        #pragma unroll
        for (int s = 0; s < 4; ++s)
          #pragma unroll
          for (int r = 0; r < 4; ++r)
            ob[(size_t)(s * 16 + g * 4 + r) * HW] = fmaf(tval, acc[s][r], bcf[s][r]);
    }
}

extern "C" void kernel_launch(void* const* d_in, const int* in_sizes, int n_in,
                              void* d_out, int out_size, void* d_ws, size_t ws_size,
                              hipStream_t stream) {
    const float* poi = (const float*)d_in[0];
    const float* tin = (const float*)d_in[1];
    const float* wm  = (const float*)d_in[2];
    const float* bm  = (const float*)d_in[3];
    const float* wf  = (const float*)d_in[4];
    const float* bf  = (const float*)d_in[5];
    const float* wc  = (const float*)d_in[6];
    const float* bc  = (const float*)d_in[7];
    float* out = (float*)d_out;

    // 1024 blocks x 256 thr = 4096 waves; 8192 tiles -> 2 tiles per wave
    hipLaunchKernelGGL(poi_mfma_kernel, dim3(1024), dim3(256), 0, stream,
                       poi, tin, wm, bm, wf, bf, wc, bc, out);
}

// Round 9
// 42.052 us; speedup vs baseline: 1.7157x; 1.7157x over previous
//
#include <hip/hip_runtime.h>
#include <hip/hip_bf16.h>

typedef short bf16x8 __attribute__((ext_vector_type(8)));
typedef float f32x4  __attribute__((ext_vector_type(4)));

constexpr int HW = 4096;   // 64*64 pixels
constexpr int CT = 31;     // time channels
constexpr int CP = 128;    // poi channels
constexpr int CO = 64;     // output channels

__device__ __forceinline__ short f2bf(float x) {
    __hip_bfloat16 h = __float2bfloat16(x);
    return *reinterpret_cast<short*>(&h);
}

// Wave = one 64-px strip (4 MFMA tiles); block = 4 waves = 256 contiguous px.
// Stage 2 swapped: A = poi fragment (M=px), B = wc fragment (N=o) so that
// D: col(lane&15)=o, row(g*4+r)=px -> each lane stores a float4 of 4 adjacent
// pixels; a wave covers 256 B contiguous per o-row => full-line writebacks.
__global__ __launch_bounds__(256)
void poi_mfma2(const float* __restrict__ poi,
               const float* __restrict__ tin,
               const float* __restrict__ wm,
               const float* __restrict__ bm,
               const float* __restrict__ wf,
               const float* __restrict__ bf,
               const float* __restrict__ wc,
               const float* __restrict__ bc,
               float* __restrict__ out)
{
    const int lane = threadIdx.x & 63;
    const int m    = lane & 15;       // free index: o (B,D-col) / px (A-row)
    const int g    = lane >> 4;       // 4-lane group: k-subrange / D row-group
    const int wid  = threadIdx.x >> 6;
    const int b    = blockIdx.x >> 4;                       // 16 blocks per image
    const int px0  = ((blockIdx.x & 15) << 8) + wid * 64;   // wave strip base

    // ---------- one-time weight fragments (identical layout to r8, verified) ----------
    bf16x8 wcf[4][4];                 // [o-subtile s][k-frag kf], used as B operand
    #pragma unroll
    for (int s = 0; s < 4; ++s)
      #pragma unroll
      for (int kf = 0; kf < 4; ++kf)
        #pragma unroll
        for (int j = 0; j < 8; ++j)
          wcf[s][kf][j] = f2bf(wc[(s * 16 + m) * CP + kf * 32 + g * 8 + j]);

    bf16x8 wmf[2];                    // wm: 32x31 padded to 32x32 (A operand, M=hidden)
    #pragma unroll
    for (int t2 = 0; t2 < 2; ++t2)
      #pragma unroll
      for (int j = 0; j < 8; ++j) {
        const int c = g * 8 + j;
        wmf[t2][j] = (c < CT) ? f2bf(wm[(t2 * 16 + m) * CT + c]) : (short)0;
      }

    float wff[8]; f32x4 bmf[2]; float bcf[4];
    #pragma unroll
    for (int t2 = 0; t2 < 2; ++t2)
      #pragma unroll
      for (int r = 0; r < 4; ++r) {
        wff[t2 * 4 + r] = wf[t2 * 16 + g * 4 + r];
        bmf[t2][r]      = bm[t2 * 16 + g * 4 + r];
      }
    #pragma unroll
    for (int s = 0; s < 4; ++s) bcf[s] = bc[s * 16 + m];    // o = s*16 + m
    const float bfv = bf[0];

    const float* tbase = tin + (size_t)b * CT * HW;
    const float* pbase = poi + (size_t)b * CP * HW;
    float*       obase = out + (size_t)b * CO * HW;

    #pragma unroll
    for (int t = 0; t < 4; ++t) {
        const int pxt = px0 + t * 16;

        // ---- stage 1: tval = relu(wf . relu(wm@time + bm) + bf) ----
        // orientation: A=wm (M=hidden), B=time (N=px via lane&15)
        const float* tb = tbase + pxt + m;
        bf16x8 tf;
        #pragma unroll
        for (int j = 0; j < 8; ++j) {
            const int c = g * 8 + j;
            tf[j] = (c < CT) ? f2bf(tb[(size_t)c * HW]) : (short)0;
        }
        f32x4 z0 = __builtin_amdgcn_mfma_f32_16x16x32_bf16(wmf[0], tf, bmf[0], 0, 0, 0);
        f32x4 z1 = __builtin_amdgcn_mfma_f32_16x16x32_bf16(wmf[1], tf, bmf[1], 0, 0, 0);
        float s1 = 0.f;
        #pragma unroll
        for (int r = 0; r < 4; ++r) {
            s1 = fmaf(fmaxf(z0[r], 0.f), wff[r],     s1);
            s1 = fmaf(fmaxf(z1[r], 0.f), wff[4 + r], s1);
        }
        s1 += __shfl_xor(s1, 16, 64);             // sum hidden across 4 lane-groups
        s1 += __shfl_xor(s1, 32, 64);
        const float tval = fmaxf(s1 + bfv, 0.f);  // valid for px = pxt + (lane&15)
        // transpose to D-row layout: tv[r] = tval at px offset g*4+r
        f32x4 tv;
        #pragma unroll
        for (int r = 0; r < 4; ++r) tv[r] = __shfl(tval, g * 4 + r, 64);

        // ---- stage 2: A = poi (M=px), B = wc (N=o), K=128 in 4 MFMAs ----
        const float* pb = pbase + pxt + m;
        bf16x8 pf[4];
        #pragma unroll
        for (int kf = 0; kf < 4; ++kf)
          #pragma unroll
          for (int j = 0; j < 8; ++j)
            pf[kf][j] = f2bf(pb[(size_t)(kf * 32 + g * 8 + j) * HW]);

        // ---- per o-subtile: MFMA, scale by tval, nontemporal float4 store ----
        float* ob = obase + pxt + g * 4;          // this lane's 4-px store base
        #pragma unroll
        for (int s = 0; s < 4; ++s) {
            f32x4 a = {0.f, 0.f, 0.f, 0.f};
            #pragma unroll
            for (int kf = 0; kf < 4; ++kf)
                a = __builtin_amdgcn_mfma_f32_16x16x32_bf16(pf[kf], wcf[s][kf], a, 0, 0, 0);
            f32x4 v;
            #pragma unroll
            for (int r = 0; r < 4; ++r) v[r] = fmaf(tv[r], a[r], bcf[s]);
            __builtin_nontemporal_store(
                v, reinterpret_cast<f32x4*>(ob + (size_t)(s * 16 + m) * HW));
        }
    }
}

extern "C" void kernel_launch(void* const* d_in, const int* in_sizes, int n_in,
                              void* d_out, int out_size, void* d_ws, size_t ws_size,
                              hipStream_t stream) {
    const float* poi = (const float*)d_in[0];
    const float* tin = (const float*)d_in[1];
    const float* wm  = (const float*)d_in[2];
    const float* bm  = (const float*)d_in[3];
    const float* wf  = (const float*)d_in[4];
    const float* bf  = (const float*)d_in[5];
    const float* wc  = (const float*)d_in[6];
    const float* bc  = (const float*)d_in[7];
    float* out = (float*)d_out;

    // 32 images x 16 blocks (256 px each) = 512 blocks of 256 threads
    hipLaunchKernelGGL(poi_mfma2, dim3(512), dim3(256), 0, stream,
                       poi, tin, wm, bm, wf, bf, wc, bc, out);
}

// Round 11
// 36.954 us; speedup vs baseline: 1.9524x; 1.1380x over previous
//
#include <hip/hip_runtime.h>
#include <hip/hip_bf16.h>

typedef short bf16x8 __attribute__((ext_vector_type(8)));
typedef float f32x4  __attribute__((ext_vector_type(4)));

constexpr int HW = 4096;   // 64*64 pixels
constexpr int CT = 31;     // time channels
constexpr int CP = 128;    // poi channels
constexpr int CO = 64;     // output channels

__device__ __forceinline__ short f2bf(float x) {
    __hip_bfloat16 h = __float2bfloat16(x);
    return *reinterpret_cast<short*>(&h);
}

// Wave = one 32-px strip (2 MFMA tiles); block = 4 waves = 128 contiguous px.
// grid = 32 images * 32 strips = 1024 blocks = 4 blocks/CU = 16 waves/CU
// (VGPR=128 allows exactly 4 waves/SIMD -> grid now fills the VGPR-allowed cap).
// Stage 2 swapped: A = poi (M=px), B = wc (N=o); lane stores float4 of 4 adjacent
// px; wave covers 128 B aligned-contiguous per o-row => full-line writebacks.
__global__ __launch_bounds__(256)
void poi_mfma3(const float* __restrict__ poi,
               const float* __restrict__ tin,
               const float* __restrict__ wm,
               const float* __restrict__ bm,
               const float* __restrict__ wf,
               const float* __restrict__ bf,
               const float* __restrict__ wc,
               const float* __restrict__ bc,
               float* __restrict__ out)
{
    const int lane = threadIdx.x & 63;
    const int m    = lane & 15;       // free index: o (B,D-col) / px (A-row)
    const int g    = lane >> 4;       // 4-lane group: k-subrange / D row-group
    const int wid  = threadIdx.x >> 6;
    const int b    = blockIdx.x >> 5;                       // 32 blocks per image
    const int px0  = ((blockIdx.x & 31) << 7) + wid * 32;   // wave strip base

    // ---------- one-time weight fragments (layout verified r8/r9) ----------
    bf16x8 wcf[4][4];                 // [o-subtile s][k-frag kf], B operand
    #pragma unroll
    for (int s = 0; s < 4; ++s)
      #pragma unroll
      for (int kf = 0; kf < 4; ++kf)
        #pragma unroll
        for (int j = 0; j < 8; ++j)
          wcf[s][kf][j] = f2bf(wc[(s * 16 + m) * CP + kf * 32 + g * 8 + j]);

    bf16x8 wmf[2];                    // wm: 32x31 padded to 32x32 (A operand)
    #pragma unroll
    for (int t2 = 0; t2 < 2; ++t2)
      #pragma unroll
      for (int j = 0; j < 8; ++j) {
        const int c = g * 8 + j;
        wmf[t2][j] = (c < CT) ? f2bf(wm[(t2 * 16 + m) * CT + c]) : (short)0;
      }

    float wff[8]; f32x4 bmf[2]; float bcf[4];
    #pragma unroll
    for (int t2 = 0; t2 < 2; ++t2)
      #pragma unroll
      for (int r = 0; r < 4; ++r) {
        wff[t2 * 4 + r] = wf[t2 * 16 + g * 4 + r];
        bmf[t2][r]      = bm[t2 * 16 + g * 4 + r];
      }
    #pragma unroll
    for (int s = 0; s < 4; ++s) bcf[s] = bc[s * 16 + m];    // o = s*16 + m
    const float bfv = bf[0];

    const float* tbase = tin + (size_t)b * CT * HW;
    const float* pbase = poi + (size_t)b * CP * HW;
    float*       obase = out + (size_t)b * CO * HW;

    #pragma unroll
    for (int t = 0; t < 2; ++t) {
        const int pxt = px0 + t * 16;

        // ---- stage 1: tval = relu(wf . relu(wm@time + bm) + bf) ----
        const float* tb = tbase + pxt + m;
        bf16x8 tf;
        #pragma unroll
        for (int j = 0; j < 8; ++j) {
            const int c = g * 8 + j;
            tf[j] = (c < CT) ? f2bf(tb[(size_t)c * HW]) : (short)0;
        }
        f32x4 z0 = __builtin_amdgcn_mfma_f32_16x16x32_bf16(wmf[0], tf, bmf[0], 0, 0, 0);
        f32x4 z1 = __builtin_amdgcn_mfma_f32_16x16x32_bf16(wmf[1], tf, bmf[1], 0, 0, 0);
        float s1 = 0.f;
        #pragma unroll
        for (int r = 0; r < 4; ++r) {
            s1 = fmaf(fmaxf(z0[r], 0.f), wff[r],     s1);
            s1 = fmaf(fmaxf(z1[r], 0.f), wff[4 + r], s1);
        }
        s1 += __shfl_xor(s1, 16, 64);             // sum hidden across lane-groups
        s1 += __shfl_xor(s1, 32, 64);
        const float tval = fmaxf(s1 + bfv, 0.f);  // valid for px = pxt + m
        // transpose to D-row layout: tv[r] = tval at px offset g*4+r
        f32x4 tv;
        #pragma unroll
        for (int r = 0; r < 4; ++r) tv[r] = __shfl(tval, g * 4 + r, 64);

        // ---- stage 2: A = poi (M=px), B = wc (N=o), K=128 in 4 MFMAs ----
        const float* pb = pbase + pxt + m;
        bf16x8 pf[4];
        #pragma unroll
        for (int kf = 0; kf < 4; ++kf)
          #pragma unroll
          for (int j = 0; j < 8; ++j)
            pf[kf][j] = f2bf(pb[(size_t)(kf * 32 + g * 8 + j) * HW]);

        // ---- per o-subtile: MFMA, scale by tval, nontemporal float4 store ----
        float* ob = obase + pxt + g * 4;          // this lane's 4-px store base
        #pragma unroll
        for (int s = 0; s < 4; ++s) {
            f32x4 a = {0.f, 0.f, 0.f, 0.f};
            #pragma unroll
            for (int kf = 0; kf < 4; ++kf)
                a = __builtin_amdgcn_mfma_f32_16x16x32_bf16(pf[kf], wcf[s][kf], a, 0, 0, 0);
            f32x4 v;
            #pragma unroll
            for (int r = 0; r < 4; ++r) v[r] = fmaf(tv[r], a[r], bcf[s]);
            __builtin_nontemporal_store(
                v, reinterpret_cast<f32x4*>(ob + (size_t)(s * 16 + m) * HW));
        }
    }
}

extern "C" void kernel_launch(void* const* d_in, const int* in_sizes, int n_in,
                              void* d_out, int out_size, void* d_ws, size_t ws_size,
                              hipStream_t stream) {
    const float* poi = (const float*)d_in[0];
    const float* tin = (const float*)d_in[1];
    const float* wm  = (const float*)d_in[2];
    const float* bm  = (const float*)d_in[3];
    const float* wf  = (const float*)d_in[4];
    const float* bf  = (const float*)d_in[5];
    const float* wc  = (const float*)d_in[6];
    const float* bc  = (const float*)d_in[7];
    float* out = (float*)d_out;

    // 32 images x 32 strips (128 px each) = 1024 blocks of 256 threads
    hipLaunchKernelGGL(poi_mfma3, dim3(1024), dim3(256), 0, stream,
                       poi, tin, wm, bm, wf, bf, wc, bc, out);
}